// Round 4
// baseline (308.258 us; speedup 1.0000x reference)
//
#include <hip/hip_runtime.h>

typedef unsigned int uint;
typedef unsigned short ushort;
typedef __bf16 bf16x8 __attribute__((ext_vector_type(8)));
typedef float f32x4 __attribute__((ext_vector_type(4)));

__device__ __forceinline__ ushort f2bf(float f) {
  union { float f; uint u; } c; c.f = f;
  uint u = c.u + 0x7fffu + ((c.u >> 16) & 1u);
  return (ushort)(u >> 16);
}
__device__ __forceinline__ float bflo(uint u) { union { uint u; float f; } c; c.u = u << 16; return c.f; }
__device__ __forceinline__ float bfhi(uint u) { union { uint u; float f; } c; c.u = u & 0xffff0000u; return c.f; }

__device__ __forceinline__ void gload16(const void* g, void* l) {
  __builtin_amdgcn_global_load_lds((const __attribute__((address_space(1))) void*)g,
                                   (__attribute__((address_space(3))) void*)l, 16, 0, 0);
}

// ---------------- cast + transpose: x [B][C][4096] f32 -> xt [B][4096][C] bf16 (both tensors) ----------------
__global__ void cast_transpose(const float* __restrict__ x1, const float* __restrict__ x2,
                               ushort* __restrict__ x1t, ushort* __restrict__ x2t) {
  __shared__ float t[32][33];
  const int z = blockIdx.z, b = z & 3, tn = z >> 2;
  const float* x = tn ? x2 : x1;
  ushort* xt = tn ? x2t : x1t;
  const int pc = blockIdx.x, cc = blockIdx.y;
  const int tx = threadIdx.x, ty = threadIdx.y; // 32 x 8
  const float* xb = x + ((size_t)b * 256 + cc * 32) * 4096 + pc * 32;
#pragma unroll
  for (int i = 0; i < 4; ++i)
    t[ty * 4 + i][tx] = xb[(size_t)(ty * 4 + i) * 4096 + tx];
  __syncthreads();
  ushort* xtb = xt + ((size_t)b * 4096 + pc * 32) * 256 + cc * 32;
#pragma unroll
  for (int i = 0; i < 4; ++i)
    xtb[(size_t)(ty * 4 + i) * 256 + tx] = f2bf(t[tx][ty * 4 + i]);
}

// ---------------- all weights -> bf16, one kernel. Q weights get 1/sqrt(C)*log2(e) folded in. ----------------
__global__ void cast_weights(const float* __restrict__ w1, const float* __restrict__ w2,
                             const float* __restrict__ wqkv, const float* __restrict__ wout,
                             const float* __restrict__ wsk,
                             ushort* __restrict__ w1b, ushort* __restrict__ w2b,
                             ushort* __restrict__ wqb, ushort* __restrict__ wkvb,
                             ushort* __restrict__ woutb, ushort* __restrict__ wskb) {
  const int i = blockIdx.x * 256 + threadIdx.x;
  const float QS = 0.0625f * 1.44269504088896f;
  if (i < 65536) w1b[i] = f2bf(w1[i]);
  else if (i < 131072) w2b[i - 65536] = f2bf(w2[i - 65536]);
  else if (i < 196608) wqb[i - 131072] = f2bf(wqkv[i - 131072] * QS);
  else if (i < 327680) wkvb[i - 196608] = f2bf(wqkv[i - 131072]);
  else if (i < 393216) woutb[i - 327680] = f2bf(wout[i - 327680]);
  else wskb[i - 393216] = f2bf(wsk[i - 393216]);
}

// ---------------- GroupNorm on pixel-major bf16 [B][4096][256], G=32 (8 ch/group); z selects tensor ----------------
__global__ void groupnorm(const ushort* __restrict__ y1, ushort* __restrict__ o1,
                          const ushort* __restrict__ y2,
                          const float* __restrict__ gamma, const float* __restrict__ beta) {
  const int g = blockIdx.x, b = blockIdx.y, tn = blockIdx.z;
  const ushort* y = tn ? y2 : y1;
  ushort* gout = tn ? (ushort*)y2 : o1;
  const int tid = threadIdx.x; // 256
  const size_t base = ((size_t)b * 4096) * 256 + g * 8;
  float s = 0.f, ss = 0.f;
#pragma unroll
  for (int i = 0; i < 16; ++i) {
    int p = i * 256 + tid;
    uint4 raw = *(const uint4*)(y + base + (size_t)p * 256);
    float v0 = bflo(raw.x), v1 = bfhi(raw.x), v2 = bflo(raw.y), v3 = bfhi(raw.y);
    float v4 = bflo(raw.z), v5 = bfhi(raw.z), v6 = bflo(raw.w), v7 = bfhi(raw.w);
    s += v0 + v1 + v2 + v3 + v4 + v5 + v6 + v7;
    ss += v0 * v0 + v1 * v1 + v2 * v2 + v3 * v3 + v4 * v4 + v5 * v5 + v6 * v6 + v7 * v7;
  }
#pragma unroll
  for (int off = 1; off < 64; off <<= 1) { s += __shfl_xor(s, off); ss += __shfl_xor(ss, off); }
  __shared__ float red[10];
  if ((tid & 63) == 0) { red[tid >> 6] = s; red[4 + (tid >> 6)] = ss; }
  __syncthreads();
  if (tid == 0) {
    float S = red[0] + red[1] + red[2] + red[3];
    float SS = red[4] + red[5] + red[6] + red[7];
    float mu = S * (1.f / 32768.f);
    float var = SS * (1.f / 32768.f) - mu * mu;
    red[8] = mu; red[9] = rsqrtf(var + 1e-5f);
  }
  __syncthreads();
  const float mu = red[8], rstd = red[9];
  float ga[8], be[8];
#pragma unroll
  for (int j = 0; j < 8; ++j) { ga[j] = gamma[g * 8 + j]; be[j] = beta[g * 8 + j]; }
#pragma unroll
  for (int i = 0; i < 16; ++i) {
    int p = i * 256 + tid;
    const size_t off = base + (size_t)p * 256;
    uint4 raw = *(const uint4*)(y + off);
    float v[8] = { bflo(raw.x), bfhi(raw.x), bflo(raw.y), bfhi(raw.y),
                   bflo(raw.z), bfhi(raw.z), bflo(raw.w), bfhi(raw.w) };
    ushort o[8];
#pragma unroll
    for (int j = 0; j < 8; ++j) o[j] = f2bf((v[j] - mu) * rstd * ga[j] + be[j]);
    uint4 w;
    w.x = (uint)o[0] | ((uint)o[1] << 16); w.y = (uint)o[2] | ((uint)o[3] << 16);
    w.z = (uint)o[4] | ((uint)o[5] << 16); w.w = (uint)o[6] | ((uint)o[7] << 16);
    *(uint4*)(gout + off) = w;
  }
}

// ---------------- shared GEMM pieces: 128x128 tile, K-step 64, double-buffered LDS ----------------
__device__ __forceinline__ void g_stage(const ushort* __restrict__ A, const ushort* __restrict__ W,
                                        int m0, int n0, int ko, ushort* al, ushort* bl, int w, int l) {
#pragma unroll
  for (int j = 0; j < 4; ++j) {
    int cb = (j * 4 + w) * 64;
    int chunk = cb + l;
    int row = chunk >> 3, sl = chunk & 7;
    int col = (sl * 8) ^ ((row & 7) << 3);
    gload16(A + (size_t)(m0 + row) * 256 + ko + col, al + cb * 8);
  }
#pragma unroll
  for (int j = 0; j < 4; ++j) {
    int cb = (j * 4 + w) * 64;
    int chunk = cb + l;
    int row = chunk >> 3, sl = chunk & 7;
    int col = (sl * 8) ^ ((row & 7) << 3);
    gload16(W + (size_t)(n0 + row) * 256 + ko + col, bl + cb * 8);
  }
}

__device__ __forceinline__ void g_compute(const ushort* al, const ushort* bl,
                                          int wr, int wc, int lr, int lg, f32x4 acc[4][4]) {
#pragma unroll
  for (int kk = 0; kk < 2; ++kk) {
    bf16x8 af[4], bfr[4];
#pragma unroll
    for (int m = 0; m < 4; ++m)
      af[m] = *(const bf16x8*)&al[(wr * 64 + m * 16 + lr) * 64 + ((kk * 32 + lg * 8) ^ ((lr & 7) << 3))];
#pragma unroll
    for (int n = 0; n < 4; ++n)
      bfr[n] = *(const bf16x8*)&bl[(wc * 64 + n * 16 + lr) * 64 + ((kk * 32 + lg * 8) ^ ((lr & 7) << 3))];
#pragma unroll
    for (int m = 0; m < 4; ++m)
#pragma unroll
      for (int n = 0; n < 4; ++n)
        acc[m][n] = __builtin_amdgcn_mfma_f32_16x16x32_bf16(af[m], bfr[n], acc[m][n], 0, 0, 0);
  }
}

// ---------------- conv1 + conv2 fused: z = t*4 + b ----------------
__launch_bounds__(256)
__global__ void conv_pair(const ushort* __restrict__ x1t, const ushort* __restrict__ x2t,
                          const ushort* __restrict__ w1b, const ushort* __restrict__ w2b,
                          const float* __restrict__ b1, const float* __restrict__ b2,
                          ushort* __restrict__ y1t, ushort* __restrict__ y2t) {
  __shared__ ushort al[2][8192];
  __shared__ ushort bl[2][8192];
  const int z = blockIdx.z, b = z & 3, t = z >> 2;
  const ushort* A = (t ? x2t : x1t) + (size_t)b * 4096 * 256;
  const ushort* W = t ? w2b : w1b;
  const float* bias = t ? b2 : b1;
  ushort* out = t ? y2t : y1t;
  const int m0 = blockIdx.y * 128, n0 = blockIdx.x * 128;
  const int tid = threadIdx.x, w = tid >> 6, l = tid & 63;
  const int wr = w >> 1, wc = w & 1, lr = l & 15, lg = l >> 4;
  f32x4 acc[4][4] = {};
  g_stage(A, W, m0, n0, 0, al[0], bl[0], w, l);
  __syncthreads();
  for (int s = 0; s < 4; ++s) {
    int cur = s & 1;
    if (s + 1 < 4) g_stage(A, W, m0, n0, (s + 1) * 64, al[cur ^ 1], bl[cur ^ 1], w, l);
    g_compute(al[cur], bl[cur], wr, wc, lr, lg, acc);
    __syncthreads();
  }
#pragma unroll
  for (int n = 0; n < 4; ++n) {
    int o = n0 + wc * 64 + n * 16 + lr;
    float bv = bias[o];
#pragma unroll
    for (int m = 0; m < 4; ++m) {
      int p0 = m0 + wr * 64 + m * 16 + lg * 4;
#pragma unroll
      for (int r = 0; r < 4; ++r)
        out[((size_t)b * 4096 + p0 + r) * 256 + o] = f2bf(acc[m][n][r] + bv);
    }
  }
}

// ---------------- q-proj + kv-proj fused: x<2 -> q1 (from g1t), x>=2 -> [k2|v2] (from y2t) ----------------
__launch_bounds__(256)
__global__ void gemm_qkv(const ushort* __restrict__ g1t, const ushort* __restrict__ y2t,
                         const ushort* __restrict__ wqb, const ushort* __restrict__ wkvb,
                         ushort* __restrict__ q1t, ushort* __restrict__ k2t, ushort* __restrict__ v2) {
  __shared__ ushort al[2][8192];
  __shared__ ushort bl[2][8192];
  const int b = blockIdx.z, x = blockIdx.x;
  const bool isq = x < 2;
  const ushort* A = (isq ? g1t : y2t) + (size_t)b * 4096 * 256;
  const ushort* W = isq ? wqb : wkvb;
  const int n0 = isq ? x * 128 : (x - 2) * 128;
  const int m0 = blockIdx.y * 128;
  const int tid = threadIdx.x, w = tid >> 6, l = tid & 63;
  const int wr = w >> 1, wc = w & 1, lr = l & 15, lg = l >> 4;
  f32x4 acc[4][4] = {};
  g_stage(A, W, m0, n0, 0, al[0], bl[0], w, l);
  __syncthreads();
  for (int s = 0; s < 4; ++s) {
    int cur = s & 1;
    if (s + 1 < 4) g_stage(A, W, m0, n0, (s + 1) * 64, al[cur ^ 1], bl[cur ^ 1], w, l);
    g_compute(al[cur], bl[cur], wr, wc, lr, lg, acc);
    __syncthreads();
  }
#pragma unroll
  for (int n = 0; n < 4; ++n) {
    int o = n0 + wc * 64 + n * 16 + lr;
#pragma unroll
    for (int m = 0; m < 4; ++m) {
      int p0 = m0 + wr * 64 + m * 16 + lg * 4;
#pragma unroll
      for (int r = 0; r < 4; ++r) {
        float val = acc[m][n][r];
        int p = p0 + r;
        if (isq) q1t[((size_t)b * 4096 + p) * 256 + o] = f2bf(val);
        else if (o < 256) k2t[((size_t)b * 4096 + p) * 256 + o] = f2bf(val);
        else v2[((size_t)b * 256 + (o - 256)) * 4096 + p] = f2bf(val);
      }
    }
  }
}

// ---------------- final: out = ot@wout^T + bout + y1@wsk^T + bsk, f32 channel-major ----------------
__launch_bounds__(256)
__global__ void gemm_final(const ushort* __restrict__ ot, const ushort* __restrict__ y1t,
                           const ushort* __restrict__ woutb, const ushort* __restrict__ wskb,
                           const float* __restrict__ bout, const float* __restrict__ bsk,
                           float* __restrict__ out) {
  __shared__ ushort smem[32768]; // 64KB: 2 A-bufs, 2 B-bufs; reused as f32 C-bounce
  ushort* al0 = smem;            ushort* al1 = smem + 8192;
  ushort* bl0 = smem + 16384;    ushort* bl1 = smem + 24576;
  const int b = blockIdx.z;
  const int m0 = blockIdx.y * 128, n0 = blockIdx.x * 128;
  const int tid = threadIdx.x, w = tid >> 6, l = tid & 63;
  const int wr = w >> 1, wc = w & 1, lr = l & 15, lg = l >> 4;
  const ushort* A0 = ot + (size_t)b * 4096 * 256;
  const ushort* A1 = y1t + (size_t)b * 4096 * 256;
  f32x4 acc[4][4] = {};
  g_stage(A0, woutb, m0, n0, 0, al0, bl0, w, l);
  __syncthreads();
  for (int s = 0; s < 8; ++s) {
    int cur = s & 1;
    if (s + 1 < 8) {
      const ushort* A = (s + 1 >= 4) ? A1 : A0;
      const ushort* W = (s + 1 >= 4) ? wskb : woutb;
      g_stage(A, W, m0, n0, ((s + 1) & 3) * 64, cur ? al0 : al1, cur ? bl0 : bl1, w, l);
    }
    g_compute(cur ? al1 : al0, cur ? bl1 : bl0, wr, wc, lr, lg, acc);
    __syncthreads();
  }
  // epilogue: bias, LDS transpose bounce (swizzled), coalesced f32 writes
  float4* cl = (float4*)smem; // [128 o][32 f4]
#pragma unroll
  for (int n = 0; n < 4; ++n) {
    int o = wc * 64 + n * 16 + lr;
    float bv = bout[n0 + o] + bsk[n0 + o];
#pragma unroll
    for (int m = 0; m < 4; ++m) {
      int pf4 = wr * 16 + m * 4 + lg;
      f32x4 v = acc[m][n];
      float4 vv; vv.x = v[0] + bv; vv.y = v[1] + bv; vv.z = v[2] + bv; vv.w = v[3] + bv;
      cl[o * 32 + (pf4 ^ (o & 31))] = vv;
    }
  }
  __syncthreads();
  float4* og = (float4*)(out + ((size_t)b * 256 + n0) * 4096 + m0);
#pragma unroll
  for (int i = 0; i < 16; ++i) {
    int o = i * 8 + (tid >> 5);
    int f4 = tid & 31;
    og[(size_t)o * 1024 + f4] = cl[o * 32 + (f4 ^ (o & 31))];
  }
}

// ---------------- flash attention, d-split 2-way, KVBLK=32 -> 52KB LDS -> 2 blocks/CU ----------------
// Q [B][4096][256] (pre-scaled), K [B][4096][256], V [B][256][4096] -> O [B][4096][256] bf16.
// Grid 512: xcd=bid&7 -> b=xcd>>1 (batch-affine L2); slot=bid>>3: h=slot&1 (d-half), qt=(xcd&1)*32+(slot>>1).
// Each block: 64 q rows, full QK^T+softmax (duplicated across halves), PV for 128 of 256 d-channels.
__launch_bounds__(256)
__global__ void attn(const ushort* __restrict__ Q, const ushort* __restrict__ K,
                     const ushort* __restrict__ V, ushort* __restrict__ O) {
  __shared__ ushort kb[2][32 * 256];
  __shared__ ushort vb[2][128 * 32];
  __shared__ ushort p_lds[64 * 32];
  const int bid = blockIdx.x;
  const int xcd = bid & 7, slot = bid >> 3;
  const int b = xcd >> 1;
  const int h = slot & 1;
  const int qt = (xcd & 1) * 32 + (slot >> 1);
  const int tid = threadIdx.x;
  const int w = tid >> 6, l = tid & 63;
  const int lr = l & 15, lg = l >> 4;

  const ushort* Qb = Q + (size_t)b * 4096 * 256;
  const ushort* Kb = K + (size_t)b * 4096 * 256;
  const ushort* Vb = V + (size_t)b * 256 * 4096 + (size_t)h * 128 * 4096;

  // stage Q tile [64][256] through kb (32KB contiguous bounce)
  ushort* qld = &kb[0][0];
#pragma unroll
  for (int j = 0; j < 8; ++j) {
    int cb = (j * 4 + w) * 64;
    int chunk = cb + l;
    int row = chunk >> 5, sl = chunk & 31;
    int col = (sl * 8) ^ ((row & 15) << 4);
    gload16(Qb + (size_t)(qt * 64 + row) * 256 + col, qld + (size_t)cb * 8);
  }
  __syncthreads();
  bf16x8 qf[8];
#pragma unroll
  for (int kk = 0; kk < 8; ++kk)
    qf[kk] = *(const bf16x8*)&qld[(w * 16 + lr) * 256 + ((kk * 32 + lg * 8) ^ (lr << 4))];
  __syncthreads(); // qf reads complete before K0 overwrites the bounce region

  auto stageK = [&](int kt, int buf) {
#pragma unroll
    for (int j = 0; j < 4; ++j) {
      int cb = (j * 4 + w) * 64;
      int chunk = cb + l;
      int row = chunk >> 5, sl = chunk & 31;
      int col = (sl * 8) ^ ((row & 15) << 4);
      gload16(Kb + (size_t)(kt * 32 + row) * 256 + col, &kb[buf][cb * 8]);
    }
  };
  auto stageV = [&](int kt, int buf) {
#pragma unroll
    for (int j = 0; j < 2; ++j) {
      int cb = (j * 4 + w) * 64;
      int chunk = cb + l;
      int row = chunk >> 2, sl = chunk & 3;
      int col = (sl ^ ((row >> 1) & 3)) << 3;
      gload16(Vb + (size_t)row * 4096 + kt * 32 + col, &vb[buf][cb * 8]);
    }
  };

  stageK(0, 0);
  stageV(0, 0);
  __syncthreads();

  float mrow = -1e30f, lsum = 0.f;
  f32x4 oacc[8] = {};

  for (int kt = 0; kt < 128; ++kt) {
    const int cur = kt & 1;
    if (kt + 1 < 128) { stageK(kt + 1, cur ^ 1); stageV(kt + 1, cur ^ 1); }
    const ushort* kl = kb[cur];
    const ushort* vl = vb[cur];

    // S^T: lane holds S[k = n*16+lg*4+r][q = w*16+lr]
    f32x4 s[2] = {};
#pragma unroll
    for (int kk = 0; kk < 8; ++kk) {
#pragma unroll
      for (int n = 0; n < 2; ++n) {
        bf16x8 kv = *(const bf16x8*)&kl[(n * 16 + lr) * 256 + ((kk * 32 + lg * 8) ^ (lr << 4))];
        s[n] = __builtin_amdgcn_mfma_f32_16x16x32_bf16(kv, qf[kk], s[n], 0, 0, 0);
      }
    }

    float tm = fmaxf(fmaxf(fmaxf(s[0][0], s[0][1]), fmaxf(s[0][2], s[0][3])),
                     fmaxf(fmaxf(s[1][0], s[1][1]), fmaxf(s[1][2], s[1][3])));
    tm = fmaxf(tm, __shfl_xor(tm, 16));
    tm = fmaxf(tm, __shfl_xor(tm, 32));

    if (__any(tm > mrow + 11.5f)) { // defer-max (exp2 headroom 2^11.5)
      float mn = fmaxf(mrow, tm);
      float alpha = exp2f(mrow - mn);
      mrow = mn;
      lsum *= alpha;
      float ar[4];
#pragma unroll
      for (int r = 0; r < 4; ++r) ar[r] = __shfl(alpha, lg * 4 + r);
#pragma unroll
      for (int nf = 0; nf < 8; ++nf)
#pragma unroll
        for (int r = 0; r < 4; ++r) oacc[nf][r] *= ar[r];
    }

    const int prow = w * 16 + lr;
    const int psw = (prow >> 1) & 3;
#pragma unroll
    for (int n = 0; n < 2; ++n) {
      float p0 = exp2f(s[n][0] - mrow), p1 = exp2f(s[n][1] - mrow);
      float p2 = exp2f(s[n][2] - mrow), p3 = exp2f(s[n][3] - mrow);
      lsum += (p0 + p1) + (p2 + p3);
      uint2 pk;
      pk.x = (uint)f2bf(p0) | ((uint)f2bf(p1) << 16);
      pk.y = (uint)f2bf(p2) | ((uint)f2bf(p3) << 16);
      *(uint2*)&p_lds[prow * 32 + (((n * 2 + (lg >> 1)) ^ psw) << 3) + (lg & 1) * 4] = pk;
    }

    bf16x8 pa = *(const bf16x8*)&p_lds[prow * 32 + ((lg ^ psw) << 3)];
#pragma unroll
    for (int nf = 0; nf < 8; ++nf) {
      int vrow = nf * 16 + lr;
      bf16x8 vv = *(const bf16x8*)&vl[vrow * 32 + ((lg ^ ((vrow >> 1) & 3)) << 3)];
      oacc[nf] = __builtin_amdgcn_mfma_f32_16x16x32_bf16(pa, vv, oacc[nf], 0, 0, 0);
    }
    __syncthreads();
  }

  float ls = lsum;
  ls += __shfl_xor(ls, 16);
  ls += __shfl_xor(ls, 32);
  float inv[4];
#pragma unroll
  for (int r = 0; r < 4; ++r) inv[r] = 1.f / __shfl(ls, lg * 4 + r);

  ushort* Ob = O + (size_t)b * 4096 * 256 + h * 128;
#pragma unroll
  for (int nf = 0; nf < 8; ++nf) {
#pragma unroll
    for (int r = 0; r < 4; ++r) {
      int qp = qt * 64 + w * 16 + lg * 4 + r;
      Ob[(size_t)qp * 256 + nf * 16 + lr] = f2bf(oacc[nf][r] * inv[r]);
    }
  }
}

extern "C" void kernel_launch(void* const* d_in, const int* in_sizes, int n_in,
                              void* d_out, int out_size, void* d_ws, size_t ws_size,
                              hipStream_t stream) {
  const float* x1 = (const float*)d_in[0];
  const float* x2 = (const float*)d_in[1];
  const float* w1 = (const float*)d_in[2];
  const float* b1 = (const float*)d_in[3];
  const float* w2 = (const float*)d_in[4];
  const float* b2 = (const float*)d_in[5];
  const float* gn_w = (const float*)d_in[6];
  const float* gn_b = (const float*)d_in[7];
  const float* wqkv = (const float*)d_in[8];
  const float* wout = (const float*)d_in[9];
  const float* bout = (const float*)d_in[10];
  const float* wsk = (const float*)d_in[11];
  const float* bsk = (const float*)d_in[12];
  float* out = (float*)d_out;

  const size_t NB = (size_t)4 * 4096 * 256;
  ushort* x1t = (ushort*)d_ws;      // later reused as q1t
  ushort* x2t = x1t + NB;           // later reused as k2t
  ushort* y1t = x2t + NB;           // persists (skip input)
  ushort* y2t = y1t + NB;           // GN'd in place -> g2t
  ushort* g1t = y2t + NB;           // later reused as attn output
  ushort* v2  = g1t + NB;
  ushort* w1b = v2 + NB;
  ushort* w2b = w1b + 65536;
  ushort* wqb = w2b + 65536;
  ushort* wkvb = wqb + 65536;       // 131072
  ushort* woutb = wkvb + 131072;
  ushort* wskb = woutb + 65536;

  cast_transpose<<<dim3(128, 8, 8), dim3(32, 8), 0, stream>>>(x1, x2, x1t, x2t);
  cast_weights<<<1792, 256, 0, stream>>>(w1, w2, wqkv, wout, wsk,
                                         w1b, w2b, wqb, wkvb, woutb, wskb);
  conv_pair<<<dim3(2, 32, 8), 256, 0, stream>>>(x1t, x2t, w1b, w2b, b1, b2, y1t, y2t);
  groupnorm<<<dim3(32, 4, 2), 256, 0, stream>>>(y1t, g1t, y2t, gn_w, gn_b);
  gemm_qkv<<<dim3(6, 32, 4), 256, 0, stream>>>(g1t, y2t, wqb, wkvb, x1t, x2t, v2);
  attn<<<512, 256, 0, stream>>>(x1t, x2t, v2, g1t);
  gemm_final<<<dim3(2, 32, 4), 256, 0, stream>>>(g1t, y1t, woutb, wskb, bout, bsk, out);
}

// Round 5
// 269.888 us; speedup vs baseline: 1.1422x; 1.1422x over previous
//
#include <hip/hip_runtime.h>

typedef unsigned int uint;
typedef unsigned short ushort;
typedef __bf16 bf16x8 __attribute__((ext_vector_type(8)));
typedef short s16x4 __attribute__((ext_vector_type(4)));
typedef float f32x4 __attribute__((ext_vector_type(4)));

__device__ __forceinline__ ushort f2bf(float f) {
  union { float f; uint u; } c; c.f = f;
  uint u = c.u + 0x7fffu + ((c.u >> 16) & 1u);
  return (ushort)(u >> 16);
}
__device__ __forceinline__ float bflo(uint u) { union { uint u; float f; } c; c.u = u << 16; return c.f; }
__device__ __forceinline__ float bfhi(uint u) { union { uint u; float f; } c; c.u = u & 0xffff0000u; return c.f; }

__device__ __forceinline__ void gload16(const void* g, void* l) {
  __builtin_amdgcn_global_load_lds((const __attribute__((address_space(1))) void*)g,
                                   (__attribute__((address_space(3))) void*)l, 16, 0, 0);
}
// D = A*B^T + D via v_mfma_f32_16x16x16_bf16 (A,B: 4 bf16 = 2 VGPR each)
__device__ __forceinline__ void mfma16(f32x4& acc, s16x4 a, s16x4 b) {
  asm("v_mfma_f32_16x16x16_bf16 %0, %1, %2, %0" : "+v"(acc) : "v"(a), "v"(b));
}

// ---------------- cast + transpose: x [B][C][4096] f32 -> xt [B][4096][C] bf16 (both tensors) ----------------
__global__ void cast_transpose(const float* __restrict__ x1, const float* __restrict__ x2,
                               ushort* __restrict__ x1t, ushort* __restrict__ x2t) {
  __shared__ float t[32][33];
  const int z = blockIdx.z, b = z & 3, tn = z >> 2;
  const float* x = tn ? x2 : x1;
  ushort* xt = tn ? x2t : x1t;
  const int pc = blockIdx.x, cc = blockIdx.y;
  const int tx = threadIdx.x, ty = threadIdx.y; // 32 x 8
  const float* xb = x + ((size_t)b * 256 + cc * 32) * 4096 + pc * 32;
#pragma unroll
  for (int i = 0; i < 4; ++i)
    t[ty * 4 + i][tx] = xb[(size_t)(ty * 4 + i) * 4096 + tx];
  __syncthreads();
  ushort* xtb = xt + ((size_t)b * 4096 + pc * 32) * 256 + cc * 32;
#pragma unroll
  for (int i = 0; i < 4; ++i)
    xtb[(size_t)(ty * 4 + i) * 256 + tx] = f2bf(t[tx][ty * 4 + i]);
}

// ---------------- all weights -> bf16, one kernel. Q weights get 1/sqrt(C)*log2(e) folded in. ----------------
__global__ void cast_weights(const float* __restrict__ w1, const float* __restrict__ w2,
                             const float* __restrict__ wqkv, const float* __restrict__ wout,
                             const float* __restrict__ wsk,
                             ushort* __restrict__ w1b, ushort* __restrict__ w2b,
                             ushort* __restrict__ wqb, ushort* __restrict__ wkvb,
                             ushort* __restrict__ woutb, ushort* __restrict__ wskb) {
  const int i = blockIdx.x * 256 + threadIdx.x;
  const float QS = 0.0625f * 1.44269504088896f;
  if (i < 65536) w1b[i] = f2bf(w1[i]);
  else if (i < 131072) w2b[i - 65536] = f2bf(w2[i - 65536]);
  else if (i < 196608) wqb[i - 131072] = f2bf(wqkv[i - 131072] * QS);
  else if (i < 327680) wkvb[i - 196608] = f2bf(wqkv[i - 131072]);
  else if (i < 393216) woutb[i - 327680] = f2bf(wout[i - 327680]);
  else wskb[i - 393216] = f2bf(wsk[i - 393216]);
}

// ---------------- GroupNorm on pixel-major bf16 [B][4096][256], G=32 (8 ch/group); z selects tensor ----------------
__global__ void groupnorm(const ushort* __restrict__ y1, ushort* __restrict__ o1,
                          const ushort* __restrict__ y2,
                          const float* __restrict__ gamma, const float* __restrict__ beta) {
  const int g = blockIdx.x, b = blockIdx.y, tn = blockIdx.z;
  const ushort* y = tn ? y2 : y1;
  ushort* gout = tn ? (ushort*)y2 : o1;
  const int tid = threadIdx.x; // 256
  const size_t base = ((size_t)b * 4096) * 256 + g * 8;
  float s = 0.f, ss = 0.f;
#pragma unroll
  for (int i = 0; i < 16; ++i) {
    int p = i * 256 + tid;
    uint4 raw = *(const uint4*)(y + base + (size_t)p * 256);
    float v0 = bflo(raw.x), v1 = bfhi(raw.x), v2 = bflo(raw.y), v3 = bfhi(raw.y);
    float v4 = bflo(raw.z), v5 = bfhi(raw.z), v6 = bflo(raw.w), v7 = bfhi(raw.w);
    s += v0 + v1 + v2 + v3 + v4 + v5 + v6 + v7;
    ss += v0 * v0 + v1 * v1 + v2 * v2 + v3 * v3 + v4 * v4 + v5 * v5 + v6 * v6 + v7 * v7;
  }
#pragma unroll
  for (int off = 1; off < 64; off <<= 1) { s += __shfl_xor(s, off); ss += __shfl_xor(ss, off); }
  __shared__ float red[10];
  if ((tid & 63) == 0) { red[tid >> 6] = s; red[4 + (tid >> 6)] = ss; }
  __syncthreads();
  if (tid == 0) {
    float S = red[0] + red[1] + red[2] + red[3];
    float SS = red[4] + red[5] + red[6] + red[7];
    float mu = S * (1.f / 32768.f);
    float var = SS * (1.f / 32768.f) - mu * mu;
    red[8] = mu; red[9] = rsqrtf(var + 1e-5f);
  }
  __syncthreads();
  const float mu = red[8], rstd = red[9];
  float ga[8], be[8];
#pragma unroll
  for (int j = 0; j < 8; ++j) { ga[j] = gamma[g * 8 + j]; be[j] = beta[g * 8 + j]; }
#pragma unroll
  for (int i = 0; i < 16; ++i) {
    int p = i * 256 + tid;
    const size_t off = base + (size_t)p * 256;
    uint4 raw = *(const uint4*)(y + off);
    float v[8] = { bflo(raw.x), bfhi(raw.x), bflo(raw.y), bfhi(raw.y),
                   bflo(raw.z), bfhi(raw.z), bflo(raw.w), bfhi(raw.w) };
    ushort o[8];
#pragma unroll
    for (int j = 0; j < 8; ++j) o[j] = f2bf((v[j] - mu) * rstd * ga[j] + be[j]);
    uint4 w;
    w.x = (uint)o[0] | ((uint)o[1] << 16); w.y = (uint)o[2] | ((uint)o[3] << 16);
    w.z = (uint)o[4] | ((uint)o[5] << 16); w.w = (uint)o[6] | ((uint)o[7] << 16);
    *(uint4*)(gout + off) = w;
  }
}

// ---------------- shared GEMM pieces: 128x128 tile, K-step 64, double-buffered LDS ----------------
__device__ __forceinline__ void g_stage(const ushort* __restrict__ A, const ushort* __restrict__ W,
                                        int m0, int n0, int ko, ushort* al, ushort* bl, int w, int l) {
#pragma unroll
  for (int j = 0; j < 4; ++j) {
    int cb = (j * 4 + w) * 64;
    int chunk = cb + l;
    int row = chunk >> 3, sl = chunk & 7;
    int col = (sl * 8) ^ ((row & 7) << 3);
    gload16(A + (size_t)(m0 + row) * 256 + ko + col, al + cb * 8);
  }
#pragma unroll
  for (int j = 0; j < 4; ++j) {
    int cb = (j * 4 + w) * 64;
    int chunk = cb + l;
    int row = chunk >> 3, sl = chunk & 7;
    int col = (sl * 8) ^ ((row & 7) << 3);
    gload16(W + (size_t)(n0 + row) * 256 + ko + col, bl + cb * 8);
  }
}

__device__ __forceinline__ void g_compute(const ushort* al, const ushort* bl,
                                          int wr, int wc, int lr, int lg, f32x4 acc[4][4]) {
#pragma unroll
  for (int kk = 0; kk < 2; ++kk) {
    bf16x8 af[4], bfr[4];
#pragma unroll
    for (int m = 0; m < 4; ++m)
      af[m] = *(const bf16x8*)&al[(wr * 64 + m * 16 + lr) * 64 + ((kk * 32 + lg * 8) ^ ((lr & 7) << 3))];
#pragma unroll
    for (int n = 0; n < 4; ++n)
      bfr[n] = *(const bf16x8*)&bl[(wc * 64 + n * 16 + lr) * 64 + ((kk * 32 + lg * 8) ^ ((lr & 7) << 3))];
#pragma unroll
    for (int m = 0; m < 4; ++m)
#pragma unroll
      for (int n = 0; n < 4; ++n)
        acc[m][n] = __builtin_amdgcn_mfma_f32_16x16x32_bf16(af[m], bfr[n], acc[m][n], 0, 0, 0);
  }
}

// ---------------- conv1 + conv2 fused: z = t*4 + b ----------------
__launch_bounds__(256)
__global__ void conv_pair(const ushort* __restrict__ x1t, const ushort* __restrict__ x2t,
                          const ushort* __restrict__ w1b, const ushort* __restrict__ w2b,
                          const float* __restrict__ b1, const float* __restrict__ b2,
                          ushort* __restrict__ y1t, ushort* __restrict__ y2t) {
  __shared__ ushort al[2][8192];
  __shared__ ushort bl[2][8192];
  const int z = blockIdx.z, b = z & 3, t = z >> 2;
  const ushort* A = (t ? x2t : x1t) + (size_t)b * 4096 * 256;
  const ushort* W = t ? w2b : w1b;
  const float* bias = t ? b2 : b1;
  ushort* out = t ? y2t : y1t;
  const int m0 = blockIdx.y * 128, n0 = blockIdx.x * 128;
  const int tid = threadIdx.x, w = tid >> 6, l = tid & 63;
  const int wr = w >> 1, wc = w & 1, lr = l & 15, lg = l >> 4;
  f32x4 acc[4][4] = {};
  g_stage(A, W, m0, n0, 0, al[0], bl[0], w, l);
  __syncthreads();
  for (int s = 0; s < 4; ++s) {
    int cur = s & 1;
    if (s + 1 < 4) g_stage(A, W, m0, n0, (s + 1) * 64, al[cur ^ 1], bl[cur ^ 1], w, l);
    g_compute(al[cur], bl[cur], wr, wc, lr, lg, acc);
    __syncthreads();
  }
#pragma unroll
  for (int n = 0; n < 4; ++n) {
    int o = n0 + wc * 64 + n * 16 + lr;
    float bv = bias[o];
#pragma unroll
    for (int m = 0; m < 4; ++m) {
      int p0 = m0 + wr * 64 + m * 16 + lg * 4;
#pragma unroll
      for (int r = 0; r < 4; ++r)
        out[((size_t)b * 4096 + p0 + r) * 256 + o] = f2bf(acc[m][n][r] + bv);
    }
  }
}

// ---------------- q-proj + kv-proj fused: x<2 -> q1 (from g1t), x>=2 -> [k2|v2] (from y2t) ----------------
__launch_bounds__(256)
__global__ void gemm_qkv(const ushort* __restrict__ g1t, const ushort* __restrict__ y2t,
                         const ushort* __restrict__ wqb, const ushort* __restrict__ wkvb,
                         ushort* __restrict__ q1t, ushort* __restrict__ k2t, ushort* __restrict__ v2) {
  __shared__ ushort al[2][8192];
  __shared__ ushort bl[2][8192];
  const int b = blockIdx.z, x = blockIdx.x;
  const bool isq = x < 2;
  const ushort* A = (isq ? g1t : y2t) + (size_t)b * 4096 * 256;
  const ushort* W = isq ? wqb : wkvb;
  const int n0 = isq ? x * 128 : (x - 2) * 128;
  const int m0 = blockIdx.y * 128;
  const int tid = threadIdx.x, w = tid >> 6, l = tid & 63;
  const int wr = w >> 1, wc = w & 1, lr = l & 15, lg = l >> 4;
  f32x4 acc[4][4] = {};
  g_stage(A, W, m0, n0, 0, al[0], bl[0], w, l);
  __syncthreads();
  for (int s = 0; s < 4; ++s) {
    int cur = s & 1;
    if (s + 1 < 4) g_stage(A, W, m0, n0, (s + 1) * 64, al[cur ^ 1], bl[cur ^ 1], w, l);
    g_compute(al[cur], bl[cur], wr, wc, lr, lg, acc);
    __syncthreads();
  }
#pragma unroll
  for (int n = 0; n < 4; ++n) {
    int o = n0 + wc * 64 + n * 16 + lr;
#pragma unroll
    for (int m = 0; m < 4; ++m) {
      int p0 = m0 + wr * 64 + m * 16 + lg * 4;
#pragma unroll
      for (int r = 0; r < 4; ++r) {
        float val = acc[m][n][r];
        int p = p0 + r;
        if (isq) q1t[((size_t)b * 4096 + p) * 256 + o] = f2bf(val);
        else if (o < 256) k2t[((size_t)b * 4096 + p) * 256 + o] = f2bf(val);
        else v2[((size_t)b * 256 + (o - 256)) * 4096 + p] = f2bf(val);
      }
    }
  }
}

// ---------------- final: out = ot@wout^T + bout + y1@wsk^T + bsk, f32 channel-major ----------------
__launch_bounds__(256)
__global__ void gemm_final(const ushort* __restrict__ ot, const ushort* __restrict__ y1t,
                           const ushort* __restrict__ woutb, const ushort* __restrict__ wskb,
                           const float* __restrict__ bout, const float* __restrict__ bsk,
                           float* __restrict__ out) {
  __shared__ ushort smem[32768];
  ushort* al0 = smem;            ushort* al1 = smem + 8192;
  ushort* bl0 = smem + 16384;    ushort* bl1 = smem + 24576;
  const int b = blockIdx.z;
  const int m0 = blockIdx.y * 128, n0 = blockIdx.x * 128;
  const int tid = threadIdx.x, w = tid >> 6, l = tid & 63;
  const int wr = w >> 1, wc = w & 1, lr = l & 15, lg = l >> 4;
  const ushort* A0 = ot + (size_t)b * 4096 * 256;
  const ushort* A1 = y1t + (size_t)b * 4096 * 256;
  f32x4 acc[4][4] = {};
  g_stage(A0, woutb, m0, n0, 0, al0, bl0, w, l);
  __syncthreads();
  for (int s = 0; s < 8; ++s) {
    int cur = s & 1;
    if (s + 1 < 8) {
      const ushort* A = (s + 1 >= 4) ? A1 : A0;
      const ushort* W = (s + 1 >= 4) ? wskb : woutb;
      g_stage(A, W, m0, n0, ((s + 1) & 3) * 64, cur ? al0 : al1, cur ? bl0 : bl1, w, l);
    }
    g_compute(cur ? al1 : al0, cur ? bl1 : bl0, wr, wc, lr, lg, acc);
    __syncthreads();
  }
  float4* cl = (float4*)smem; // [128 o][32 f4]
#pragma unroll
  for (int n = 0; n < 4; ++n) {
    int o = wc * 64 + n * 16 + lr;
    float bv = bout[n0 + o] + bsk[n0 + o];
#pragma unroll
    for (int m = 0; m < 4; ++m) {
      int pf4 = wr * 16 + m * 4 + lg;
      f32x4 v = acc[m][n];
      float4 vv; vv.x = v[0] + bv; vv.y = v[1] + bv; vv.z = v[2] + bv; vv.w = v[3] + bv;
      cl[o * 32 + (pf4 ^ (o & 31))] = vv;
    }
  }
  __syncthreads();
  float4* og = (float4*)(out + ((size_t)b * 256 + n0) * 4096 + m0);
#pragma unroll
  for (int i = 0; i < 16; ++i) {
    int o = i * 8 + (tid >> 5);
    int f4 = tid & 31;
    og[(size_t)o * 1024 + f4] = cl[o * 32 + (f4 ^ (o & 31))];
  }
}

// ---------------- flash attention: QBLK=64, KVBLK=64, in-register P, counted-vmcnt pipeline ----------------
// Q [B][4096][256] (pre-scaled by 1/sqrt(C)*log2e), K [B][4096][256], V [B][256][4096] -> O bf16 pixel-major.
// Grid 256, batch-affine XCD map. Q in regs (direct global loads). K triple-buffered, V double-buffered in
// LDS (160KB exactly). Raw s_barrier + counted s_waitcnt vmcnt(16): next tiles' global_load_lds stay in
// flight ACROSS the barrier (T3/T4) — never drains to 0 in the main loop.
// PV uses v_mfma_f32_16x16x16_bf16: A-slot map (k = n*16 + lg*4 + j) == exactly the S^T C/D-fragment each
// lane holds -> P handoff is 8 lane-local v_cvt_pk_bf16_f32, no LDS bounce, no cross-lane ops.
__launch_bounds__(256)
__global__ void attn(const ushort* __restrict__ Q, const ushort* __restrict__ K,
                     const ushort* __restrict__ V, ushort* __restrict__ O) {
  __shared__ ushort kb[3][64 * 256];  // 96 KB
  __shared__ ushort vb[2][256 * 64];  // 64 KB
  const int bid = blockIdx.x;
  const int xcd = bid & 7, slot = bid >> 3;
  const int b = xcd >> 1;
  const int qt = (xcd & 1) * 32 + slot;
  const int tid = threadIdx.x;
  const int w = tid >> 6, l = tid & 63;
  const int lr = l & 15, lg = l >> 4;

  const ushort* Qb = Q + (size_t)b * 4096 * 256;
  const ushort* Kb = K + (size_t)b * 4096 * 256;
  const ushort* Vb = V + (size_t)b * 256 * 4096;

  // per-lane staging offsets (hoisted out of the loop)
  int kOff[8], vOff[8];
#pragma unroll
  for (int j = 0; j < 8; ++j) {
    int chunk = (j * 4 + w) * 64 + l;
    int krow = chunk >> 5, ksl = chunk & 31;
    kOff[j] = krow * 256 + ((ksl * 8) ^ ((krow & 15) << 4));
    int vrow = chunk >> 3, vsl = chunk & 7;
    vOff[j] = vrow * 4096 + ((vsl * 8) ^ ((vrow & 7) << 3));
  }
  auto stageK = [&](int kt, ushort* dst) {
#pragma unroll
    for (int j = 0; j < 8; ++j)
      gload16(Kb + (size_t)kt * 16384 + kOff[j], dst + (j * 4 + w) * 512);
  };
  auto stageV = [&](int kt, ushort* dst) {
#pragma unroll
    for (int j = 0; j < 8; ++j)
      gload16(Vb + (size_t)kt * 64 + vOff[j], dst + (j * 4 + w) * 512);
  };

  // Q fragments straight to registers (rows are L2-resident, coalesced enough)
  bf16x8 qf[8];
  {
    const ushort* qrow = Qb + (size_t)(qt * 64 + w * 16 + lr) * 256 + lg * 8;
#pragma unroll
    for (int kk = 0; kk < 8; ++kk)
      qf[kk] = *(const bf16x8*)(qrow + kk * 32);
  }

  // prologue: K0, V0, K1 in flight; force qf+K0 complete (24 outstanding -> wait to 16)
  stageK(0, kb[0]);
  stageV(0, vb[0]);
  stageK(1, kb[1]);
  asm volatile("s_waitcnt vmcnt(16)" ::: "memory");
  __builtin_amdgcn_s_barrier();

  float mrow = -1e30f, lsum = 0.f;
  f32x4 oacc[16] = {};
  int kc = 0, kn2 = 2; // kt%3, (kt+2)%3

  for (int kt = 0; kt < 64; ++kt) {
    const ushort* kl = kb[kc];
    const ushort* vl = vb[kt & 1];

    // S^T = mfma(K, Q): lane holds S[k = n*16+lg*4+r][q = w*16+lr]
    f32x4 s[4] = {};
#pragma unroll
    for (int kk = 0; kk < 8; ++kk) {
#pragma unroll
      for (int n = 0; n < 4; ++n) {
        bf16x8 kv = *(const bf16x8*)&kl[(n * 16 + lr) * 256 + ((kk * 32 + lg * 8) ^ (lr << 4))];
        s[n] = __builtin_amdgcn_mfma_f32_16x16x32_bf16(kv, qf[kk], s[n], 0, 0, 0);
      }
    }

    // issue next tiles NOW — they stay in flight across the barrier (counted vmcnt below)
    if (kt + 2 < 64) stageK(kt + 2, kb[kn2]);
    if (kt + 1 < 64) stageV(kt + 1, vb[(kt + 1) & 1]);

    // online softmax (q-row max: 16 lane-local + 2 shfl)
    float tm = fmaxf(fmaxf(fmaxf(s[0][0], s[0][1]), fmaxf(s[0][2], s[0][3])),
                     fmaxf(fmaxf(s[1][0], s[1][1]), fmaxf(s[1][2], s[1][3])));
    tm = fmaxf(tm, fmaxf(fmaxf(fmaxf(s[2][0], s[2][1]), fmaxf(s[2][2], s[2][3])),
                         fmaxf(fmaxf(s[3][0], s[3][1]), fmaxf(s[3][2], s[3][3]))));
    tm = fmaxf(tm, __shfl_xor(tm, 16));
    tm = fmaxf(tm, __shfl_xor(tm, 32));

    if (__any(tm > mrow + 11.5f)) { // defer-max: exp2 headroom 2^11.5
      float mn = fmaxf(mrow, tm);
      float alpha = exp2f(mrow - mn);
      mrow = mn;
      lsum *= alpha;
      float ar[4];
#pragma unroll
      for (int r = 0; r < 4; ++r) ar[r] = __shfl(alpha, lg * 4 + r);
#pragma unroll
      for (int nf = 0; nf < 16; ++nf)
#pragma unroll
        for (int r = 0; r < 4; ++r) oacc[nf][r] *= ar[r];
    }

    // P = exp2(S - m): pack in-register via v_cvt_pk_bf16_f32 (lane-local PV A-fragments)
    uint pw[4][2];
#pragma unroll
    for (int n = 0; n < 4; ++n) {
      float p0 = exp2f(s[n][0] - mrow), p1 = exp2f(s[n][1] - mrow);
      float p2 = exp2f(s[n][2] - mrow), p3 = exp2f(s[n][3] - mrow);
      lsum += (p0 + p1) + (p2 + p3);
      asm("v_cvt_pk_bf16_f32 %0, %1, %2" : "=v"(pw[n][0]) : "v"(p0), "v"(p1));
      asm("v_cvt_pk_bf16_f32 %0, %1, %2" : "=v"(pw[n][1]) : "v"(p2), "v"(p3));
    }

    // counted wait: force V(kt) (and older) complete; keep the 16 newest (K(kt+2),V(kt+1)) in flight
    if (kt < 62)       asm volatile("s_waitcnt vmcnt(16)" ::: "memory");
    else if (kt == 62) asm volatile("s_waitcnt vmcnt(8)"  ::: "memory");
    else               asm volatile("s_waitcnt vmcnt(0)"  ::: "memory");

    // O += P * V : 4 x 16 mfma_16x16x16, V read as ds_read_b64 (swizzle ~2-way = free)
#pragma unroll
    for (int n = 0; n < 4; ++n) {
      uint2 pk; pk.x = pw[n][0]; pk.y = pw[n][1];
      s16x4 pa = __builtin_bit_cast(s16x4, pk);
      const int vcol = (((n * 2 + (lg >> 1)) ^ (lr & 7)) << 3) + (lg & 1) * 4;
#pragma unroll
      for (int nf = 0; nf < 16; ++nf) {
        s16x4 vv = *(const s16x4*)&vl[(nf * 16 + lr) * 64 + vcol];
        mfma16(oacc[nf], pa, vv);
      }
    }

    __builtin_amdgcn_s_barrier(); // raw barrier: in-flight loads NOT drained
    kc = (kc == 2) ? 0 : kc + 1;
    kn2 = (kn2 == 2) ? 0 : kn2 + 1;
  }

  // final row-sum reduce and O write
  float ls = lsum;
  ls += __shfl_xor(ls, 16);
  ls += __shfl_xor(ls, 32);
  float inv[4];
#pragma unroll
  for (int r = 0; r < 4; ++r) inv[r] = 1.f / __shfl(ls, lg * 4 + r);

  ushort* Ob = O + (size_t)b * 4096 * 256;
#pragma unroll
  for (int nf = 0; nf < 16; ++nf) {
#pragma unroll
    for (int r = 0; r < 4; ++r) {
      int qp = qt * 64 + w * 16 + lg * 4 + r;
      Ob[(size_t)qp * 256 + nf * 16 + lr] = f2bf(oacc[nf][r] * inv[r]);
    }
  }
}

extern "C" void kernel_launch(void* const* d_in, const int* in_sizes, int n_in,
                              void* d_out, int out_size, void* d_ws, size_t ws_size,
                              hipStream_t stream) {
  const float* x1 = (const float*)d_in[0];
  const float* x2 = (const float*)d_in[1];
  const float* w1 = (const float*)d_in[2];
  const float* b1 = (const float*)d_in[3];
  const float* w2 = (const float*)d_in[4];
  const float* b2 = (const float*)d_in[5];
  const float* gn_w = (const float*)d_in[6];
  const float* gn_b = (const float*)d_in[7];
  const float* wqkv = (const float*)d_in[8];
  const float* wout = (const float*)d_in[9];
  const float* bout = (const float*)d_in[10];
  const float* wsk = (const float*)d_in[11];
  const float* bsk = (const float*)d_in[12];
  float* out = (float*)d_out;

  const size_t NB = (size_t)4 * 4096 * 256;
  ushort* x1t = (ushort*)d_ws;      // later reused as q1t
  ushort* x2t = x1t + NB;           // later reused as k2t
  ushort* y1t = x2t + NB;           // persists (skip input)
  ushort* y2t = y1t + NB;           // GN'd in place -> g2t
  ushort* g1t = y2t + NB;           // later reused as attn output
  ushort* v2  = g1t + NB;
  ushort* w1b = v2 + NB;
  ushort* w2b = w1b + 65536;
  ushort* wqb = w2b + 65536;
  ushort* wkvb = wqb + 65536;       // 131072
  ushort* woutb = wkvb + 131072;
  ushort* wskb = woutb + 65536;

  cast_transpose<<<dim3(128, 8, 8), dim3(32, 8), 0, stream>>>(x1, x2, x1t, x2t);
  cast_weights<<<1792, 256, 0, stream>>>(w1, w2, wqkv, wout, wsk,
                                         w1b, w2b, wqb, wkvb, woutb, wskb);
  conv_pair<<<dim3(2, 32, 8), 256, 0, stream>>>(x1t, x2t, w1b, w2b, b1, b2, y1t, y2t);
  groupnorm<<<dim3(32, 4, 2), 256, 0, stream>>>(y1t, g1t, y2t, gn_w, gn_b);
  gemm_qkv<<<dim3(6, 32, 4), 256, 0, stream>>>(g1t, y2t, wqb, wkvb, x1t, x2t, v2);
  attn<<<256, 256, 0, stream>>>(x1t, x2t, v2, g1t);
  gemm_final<<<dim3(2, 32, 4), 256, 0, stream>>>(g1t, y1t, woutb, wskb, bout, bsk, out);
}

// Round 6
// 250.263 us; speedup vs baseline: 1.2317x; 1.0784x over previous
//
#include <hip/hip_runtime.h>

typedef unsigned int uint;
typedef unsigned short ushort;
typedef __bf16 bf16x8 __attribute__((ext_vector_type(8)));
typedef short s16x4 __attribute__((ext_vector_type(4)));
typedef float f32x4 __attribute__((ext_vector_type(4)));

__device__ __forceinline__ ushort f2bf(float f) {
  union { float f; uint u; } c; c.f = f;
  uint u = c.u + 0x7fffu + ((c.u >> 16) & 1u);
  return (ushort)(u >> 16);
}
__device__ __forceinline__ float bflo(uint u) { union { uint u; float f; } c; c.u = u << 16; return c.f; }
__device__ __forceinline__ float bfhi(uint u) { union { uint u; float f; } c; c.u = u & 0xffff0000u; return c.f; }

__device__ __forceinline__ void gload16(const void* g, void* l) {
  __builtin_amdgcn_global_load_lds((const __attribute__((address_space(1))) void*)g,
                                   (__attribute__((address_space(3))) void*)l, 16, 0, 0);
}
__device__ __forceinline__ void mfma16(f32x4& acc, s16x4 a, s16x4 b) {
  asm("v_mfma_f32_16x16x16_bf16 %0, %1, %2, %0" : "+v"(acc) : "v"(a), "v"(b));
}
__device__ __forceinline__ float fexp2(float x) {
  float y; asm("v_exp_f32 %0, %1" : "=v"(y) : "v"(x)); return y;
}

// ---------------- cast + transpose: x [B][C][4096] f32 -> xt [B][4096][C] bf16 (both tensors) ----------------
__global__ void cast_transpose(const float* __restrict__ x1, const float* __restrict__ x2,
                               ushort* __restrict__ x1t, ushort* __restrict__ x2t) {
  __shared__ float t[32][33];
  const int z = blockIdx.z, b = z & 3, tn = z >> 2;
  const float* x = tn ? x2 : x1;
  ushort* xt = tn ? x2t : x1t;
  const int pc = blockIdx.x, cc = blockIdx.y;
  const int tx = threadIdx.x, ty = threadIdx.y; // 32 x 8
  const float* xb = x + ((size_t)b * 256 + cc * 32) * 4096 + pc * 32;
#pragma unroll
  for (int i = 0; i < 4; ++i)
    t[ty * 4 + i][tx] = xb[(size_t)(ty * 4 + i) * 4096 + tx];
  __syncthreads();
  ushort* xtb = xt + ((size_t)b * 4096 + pc * 32) * 256 + cc * 32;
#pragma unroll
  for (int i = 0; i < 4; ++i)
    xtb[(size_t)(ty * 4 + i) * 256 + tx] = f2bf(t[tx][ty * 4 + i]);
}

// ---------------- all weights -> bf16, one kernel. Q weights get 1/sqrt(C)*log2(e) folded in. ----------------
__global__ void cast_weights(const float* __restrict__ w1, const float* __restrict__ w2,
                             const float* __restrict__ wqkv, const float* __restrict__ wout,
                             const float* __restrict__ wsk,
                             ushort* __restrict__ w1b, ushort* __restrict__ w2b,
                             ushort* __restrict__ wqb, ushort* __restrict__ wkvb,
                             ushort* __restrict__ woutb, ushort* __restrict__ wskb) {
  const int i = blockIdx.x * 256 + threadIdx.x;
  const float QS = 0.0625f * 1.44269504088896f;
  if (i < 65536) w1b[i] = f2bf(w1[i]);
  else if (i < 131072) w2b[i - 65536] = f2bf(w2[i - 65536]);
  else if (i < 196608) wqb[i - 131072] = f2bf(wqkv[i - 131072] * QS);
  else if (i < 327680) wkvb[i - 196608] = f2bf(wqkv[i - 131072]);
  else if (i < 393216) woutb[i - 327680] = f2bf(wout[i - 327680]);
  else wskb[i - 393216] = f2bf(wsk[i - 393216]);
}

// ---------------- GroupNorm on pixel-major bf16 [B][4096][256], G=32 (8 ch/group); z selects tensor ----------------
__global__ void groupnorm(const ushort* __restrict__ y1, ushort* __restrict__ o1,
                          const ushort* __restrict__ y2,
                          const float* __restrict__ gamma, const float* __restrict__ beta) {
  const int g = blockIdx.x, b = blockIdx.y, tn = blockIdx.z;
  const ushort* y = tn ? y2 : y1;
  ushort* gout = tn ? (ushort*)y2 : o1;
  const int tid = threadIdx.x; // 256
  const size_t base = ((size_t)b * 4096) * 256 + g * 8;
  float s = 0.f, ss = 0.f;
#pragma unroll
  for (int i = 0; i < 16; ++i) {
    int p = i * 256 + tid;
    uint4 raw = *(const uint4*)(y + base + (size_t)p * 256);
    float v0 = bflo(raw.x), v1 = bfhi(raw.x), v2 = bflo(raw.y), v3 = bfhi(raw.y);
    float v4 = bflo(raw.z), v5 = bfhi(raw.z), v6 = bflo(raw.w), v7 = bfhi(raw.w);
    s += v0 + v1 + v2 + v3 + v4 + v5 + v6 + v7;
    ss += v0 * v0 + v1 * v1 + v2 * v2 + v3 * v3 + v4 * v4 + v5 * v5 + v6 * v6 + v7 * v7;
  }
#pragma unroll
  for (int off = 1; off < 64; off <<= 1) { s += __shfl_xor(s, off); ss += __shfl_xor(ss, off); }
  __shared__ float red[10];
  if ((tid & 63) == 0) { red[tid >> 6] = s; red[4 + (tid >> 6)] = ss; }
  __syncthreads();
  if (tid == 0) {
    float S = red[0] + red[1] + red[2] + red[3];
    float SS = red[4] + red[5] + red[6] + red[7];
    float mu = S * (1.f / 32768.f);
    float var = SS * (1.f / 32768.f) - mu * mu;
    red[8] = mu; red[9] = rsqrtf(var + 1e-5f);
  }
  __syncthreads();
  const float mu = red[8], rstd = red[9];
  float ga[8], be[8];
#pragma unroll
  for (int j = 0; j < 8; ++j) { ga[j] = gamma[g * 8 + j]; be[j] = beta[g * 8 + j]; }
#pragma unroll
  for (int i = 0; i < 16; ++i) {
    int p = i * 256 + tid;
    const size_t off = base + (size_t)p * 256;
    uint4 raw = *(const uint4*)(y + off);
    float v[8] = { bflo(raw.x), bfhi(raw.x), bflo(raw.y), bfhi(raw.y),
                   bflo(raw.z), bfhi(raw.z), bflo(raw.w), bfhi(raw.w) };
    ushort o[8];
#pragma unroll
    for (int j = 0; j < 8; ++j) o[j] = f2bf((v[j] - mu) * rstd * ga[j] + be[j]);
    uint4 w;
    w.x = (uint)o[0] | ((uint)o[1] << 16); w.y = (uint)o[2] | ((uint)o[3] << 16);
    w.z = (uint)o[4] | ((uint)o[5] << 16); w.w = (uint)o[6] | ((uint)o[7] << 16);
    *(uint4*)(gout + off) = w;
  }
}

// ---------------- shared GEMM pieces: 128x128 tile, K-step 64, double-buffered LDS ----------------
__device__ __forceinline__ void g_stage(const ushort* __restrict__ A, const ushort* __restrict__ W,
                                        int m0, int n0, int ko, ushort* al, ushort* bl, int w, int l) {
#pragma unroll
  for (int j = 0; j < 4; ++j) {
    int cb = (j * 4 + w) * 64;
    int chunk = cb + l;
    int row = chunk >> 3, sl = chunk & 7;
    int col = (sl * 8) ^ ((row & 7) << 3);
    gload16(A + (size_t)(m0 + row) * 256 + ko + col, al + cb * 8);
  }
#pragma unroll
  for (int j = 0; j < 4; ++j) {
    int cb = (j * 4 + w) * 64;
    int chunk = cb + l;
    int row = chunk >> 3, sl = chunk & 7;
    int col = (sl * 8) ^ ((row & 7) << 3);
    gload16(W + (size_t)(n0 + row) * 256 + ko + col, bl + cb * 8);
  }
}

__device__ __forceinline__ void g_compute(const ushort* al, const ushort* bl,
                                          int wr, int wc, int lr, int lg, f32x4 acc[4][4]) {
#pragma unroll
  for (int kk = 0; kk < 2; ++kk) {
    bf16x8 af[4], bfr[4];
#pragma unroll
    for (int m = 0; m < 4; ++m)
      af[m] = *(const bf16x8*)&al[(wr * 64 + m * 16 + lr) * 64 + ((kk * 32 + lg * 8) ^ ((lr & 7) << 3))];
#pragma unroll
    for (int n = 0; n < 4; ++n)
      bfr[n] = *(const bf16x8*)&bl[(wc * 64 + n * 16 + lr) * 64 + ((kk * 32 + lg * 8) ^ ((lr & 7) << 3))];
#pragma unroll
    for (int m = 0; m < 4; ++m)
#pragma unroll
      for (int n = 0; n < 4; ++n)
        acc[m][n] = __builtin_amdgcn_mfma_f32_16x16x32_bf16(af[m], bfr[n], acc[m][n], 0, 0, 0);
  }
}

// ---------------- conv1 + conv2 fused: z = t*4 + b ----------------
__launch_bounds__(256)
__global__ void conv_pair(const ushort* __restrict__ x1t, const ushort* __restrict__ x2t,
                          const ushort* __restrict__ w1b, const ushort* __restrict__ w2b,
                          const float* __restrict__ b1, const float* __restrict__ b2,
                          ushort* __restrict__ y1t, ushort* __restrict__ y2t) {
  __shared__ ushort al[2][8192];
  __shared__ ushort bl[2][8192];
  const int z = blockIdx.z, b = z & 3, t = z >> 2;
  const ushort* A = (t ? x2t : x1t) + (size_t)b * 4096 * 256;
  const ushort* W = t ? w2b : w1b;
  const float* bias = t ? b2 : b1;
  ushort* out = t ? y2t : y1t;
  const int m0 = blockIdx.y * 128, n0 = blockIdx.x * 128;
  const int tid = threadIdx.x, w = tid >> 6, l = tid & 63;
  const int wr = w >> 1, wc = w & 1, lr = l & 15, lg = l >> 4;
  f32x4 acc[4][4] = {};
  g_stage(A, W, m0, n0, 0, al[0], bl[0], w, l);
  __syncthreads();
  for (int s = 0; s < 4; ++s) {
    int cur = s & 1;
    if (s + 1 < 4) g_stage(A, W, m0, n0, (s + 1) * 64, al[cur ^ 1], bl[cur ^ 1], w, l);
    g_compute(al[cur], bl[cur], wr, wc, lr, lg, acc);
    __syncthreads();
  }
#pragma unroll
  for (int n = 0; n < 4; ++n) {
    int o = n0 + wc * 64 + n * 16 + lr;
    float bv = bias[o];
#pragma unroll
    for (int m = 0; m < 4; ++m) {
      int p0 = m0 + wr * 64 + m * 16 + lg * 4;
#pragma unroll
      for (int r = 0; r < 4; ++r)
        out[((size_t)b * 4096 + p0 + r) * 256 + o] = f2bf(acc[m][n][r] + bv);
    }
  }
}

// ---------------- q-proj + kv-proj fused: x<2 -> q1 (from g1t), x>=2 -> [k2|v2] (from y2t) ----------------
__launch_bounds__(256)
__global__ void gemm_qkv(const ushort* __restrict__ g1t, const ushort* __restrict__ y2t,
                         const ushort* __restrict__ wqb, const ushort* __restrict__ wkvb,
                         ushort* __restrict__ q1t, ushort* __restrict__ k2t, ushort* __restrict__ v2) {
  __shared__ ushort al[2][8192];
  __shared__ ushort bl[2][8192];
  const int b = blockIdx.z, x = blockIdx.x;
  const bool isq = x < 2;
  const ushort* A = (isq ? g1t : y2t) + (size_t)b * 4096 * 256;
  const ushort* W = isq ? wqb : wkvb;
  const int n0 = isq ? x * 128 : (x - 2) * 128;
  const int m0 = blockIdx.y * 128;
  const int tid = threadIdx.x, w = tid >> 6, l = tid & 63;
  const int wr = w >> 1, wc = w & 1, lr = l & 15, lg = l >> 4;
  f32x4 acc[4][4] = {};
  g_stage(A, W, m0, n0, 0, al[0], bl[0], w, l);
  __syncthreads();
  for (int s = 0; s < 4; ++s) {
    int cur = s & 1;
    if (s + 1 < 4) g_stage(A, W, m0, n0, (s + 1) * 64, al[cur ^ 1], bl[cur ^ 1], w, l);
    g_compute(al[cur], bl[cur], wr, wc, lr, lg, acc);
    __syncthreads();
  }
#pragma unroll
  for (int n = 0; n < 4; ++n) {
    int o = n0 + wc * 64 + n * 16 + lr;
#pragma unroll
    for (int m = 0; m < 4; ++m) {
      int p0 = m0 + wr * 64 + m * 16 + lg * 4;
#pragma unroll
      for (int r = 0; r < 4; ++r) {
        float val = acc[m][n][r];
        int p = p0 + r;
        if (isq) q1t[((size_t)b * 4096 + p) * 256 + o] = f2bf(val);
        else if (o < 256) k2t[((size_t)b * 4096 + p) * 256 + o] = f2bf(val);
        else v2[((size_t)b * 256 + (o - 256)) * 4096 + p] = f2bf(val);
      }
    }
  }
}

// ---------------- final: out = ot@wout^T + bout + y1@wsk^T + bsk, f32 channel-major ----------------
__launch_bounds__(256)
__global__ void gemm_final(const ushort* __restrict__ ot, const ushort* __restrict__ y1t,
                           const ushort* __restrict__ woutb, const ushort* __restrict__ wskb,
                           const float* __restrict__ bout, const float* __restrict__ bsk,
                           float* __restrict__ out) {
  __shared__ ushort smem[32768];
  ushort* al0 = smem;            ushort* al1 = smem + 8192;
  ushort* bl0 = smem + 16384;    ushort* bl1 = smem + 24576;
  const int b = blockIdx.z;
  const int m0 = blockIdx.y * 128, n0 = blockIdx.x * 128;
  const int tid = threadIdx.x, w = tid >> 6, l = tid & 63;
  const int wr = w >> 1, wc = w & 1, lr = l & 15, lg = l >> 4;
  const ushort* A0 = ot + (size_t)b * 4096 * 256;
  const ushort* A1 = y1t + (size_t)b * 4096 * 256;
  f32x4 acc[4][4] = {};
  g_stage(A0, woutb, m0, n0, 0, al0, bl0, w, l);
  __syncthreads();
  for (int s = 0; s < 8; ++s) {
    int cur = s & 1;
    if (s + 1 < 8) {
      const ushort* A = (s + 1 >= 4) ? A1 : A0;
      const ushort* W = (s + 1 >= 4) ? wskb : woutb;
      g_stage(A, W, m0, n0, ((s + 1) & 3) * 64, cur ? al0 : al1, cur ? bl0 : bl1, w, l);
    }
    g_compute(cur ? al1 : al0, cur ? bl1 : bl0, wr, wc, lr, lg, acc);
    __syncthreads();
  }
  float4* cl = (float4*)smem; // [128 o][32 f4]
#pragma unroll
  for (int n = 0; n < 4; ++n) {
    int o = wc * 64 + n * 16 + lr;
    float bv = bout[n0 + o] + bsk[n0 + o];
#pragma unroll
    for (int m = 0; m < 4; ++m) {
      int pf4 = wr * 16 + m * 4 + lg;
      f32x4 v = acc[m][n];
      float4 vv; vv.x = v[0] + bv; vv.y = v[1] + bv; vv.z = v[2] + bv; vv.w = v[3] + bv;
      cl[o * 32 + (pf4 ^ (o & 31))] = vv;
    }
  }
  __syncthreads();
  float4* og = (float4*)(out + ((size_t)b * 256 + n0) * 4096 + m0);
#pragma unroll
  for (int i = 0; i < 16; ++i) {
    int o = i * 8 + (tid >> 5);
    int f4 = tid & 31;
    og[(size_t)o * 1024 + f4] = cl[o * 32 + (f4 ^ (o & 31))];
  }
}

// ---------------- flash attention, k-split 2-way: QBLK=64, KVBLK=32, 80KB LDS -> 2 blocks/CU ----------------
// Each block handles 2048 k-rows (kh half). Writes UNNORMALIZED partial O (bf16) + per-q-row {m, l} to ml.
// Grid 512: xcd=bid&7 -> b=xcd>>1 (batch-affine L2); r=bid>>3: kh=r&1, qt=(xcd&1)*32+(r>>1).
// K triple-buffered (3x16KB), V double-buffered (2x16KB). One counted s_waitcnt vmcnt(4) BEFORE each raw
// s_barrier (issue order V-then-K so only K(kt+2) stays in flight): cross-wave LDS visibility is provably
// ordered, K keeps ~1.5-iter prefetch depth, V ~0.5 iter.
// V LDS tile [256 d][32 k]: row-permute R = d ^ ((d>>1)&1) plus 16B-chunk XOR ((d>>1)&3) -> 2-way (free)
// ds_read_b64 despite 64B rows. PV via v_mfma_f32_16x16x16_bf16, P stays in registers (cvt_pk).
__launch_bounds__(256, 2)
__global__ void attn(const ushort* __restrict__ Q, const ushort* __restrict__ K,
                     const ushort* __restrict__ V, ushort* __restrict__ op0,
                     ushort* __restrict__ op1, float* __restrict__ ml) {
  __shared__ ushort kb[3][32 * 256];  // 48 KB
  __shared__ ushort vb[2][256 * 32];  // 32 KB
  const int bid = blockIdx.x;
  const int xcd = bid & 7, r = bid >> 3;
  const int b = xcd >> 1;
  const int kh = r & 1;
  const int qt = (xcd & 1) * 32 + (r >> 1);
  const int tid = threadIdx.x;
  const int w = tid >> 6, l = tid & 63;
  const int lr = l & 15, lg = l >> 4;

  const ushort* Qb = Q + (size_t)b * 4096 * 256;
  const ushort* Kb = K + (size_t)b * 4096 * 256 + (size_t)kh * 2048 * 256;
  const ushort* Vb = V + (size_t)b * 256 * 4096 + kh * 2048;

  // per-lane staging source offsets (pre-swizzled global source, linear LDS dest)
  int kOff[4], vOff[4];
#pragma unroll
  for (int j = 0; j < 4; ++j) {
    int c = (j * 4 + w) * 64 + l;
    int krow = c >> 5, ksl = c & 31;
    kOff[j] = krow * 256 + ((ksl * 8) ^ ((krow & 15) << 4));
    int R = c >> 2, CH = c & 3;
    int vd = R ^ ((R >> 1) & 1);
    int gch = CH ^ ((R >> 1) & 3);
    vOff[j] = vd * 4096 + gch * 8;
  }
  auto stageK = [&](int kt, ushort* dst) {
#pragma unroll
    for (int j = 0; j < 4; ++j)
      gload16(Kb + (size_t)kt * 8192 + kOff[j], dst + (j * 4 + w) * 512);
  };
  auto stageV = [&](int kt, ushort* dst) {
#pragma unroll
    for (int j = 0; j < 4; ++j)
      gload16(Vb + (size_t)kt * 32 + vOff[j], dst + (j * 4 + w) * 512);
  };

  // Q fragments straight to registers (issued first so the prologue vmcnt drains them)
  bf16x8 qf[8];
  {
    const ushort* qrow = Qb + (size_t)(qt * 64 + w * 16 + lr) * 256 + lg * 8;
#pragma unroll
    for (int kk = 0; kk < 8; ++kk)
      qf[kk] = *(const bf16x8*)(qrow + kk * 32);
  }

  // prologue: K0, V0 complete; K1 in flight
  stageK(0, kb[0]);
  stageV(0, vb[0]);
  stageK(1, kb[1]);
  asm volatile("s_waitcnt vmcnt(4)" ::: "memory");
  __builtin_amdgcn_s_barrier();

  // lane-constant pieces of the V read address
  const int lrp = lr ^ ((lr >> 1) & 1);
  const int vsw = (lr >> 1) & 3;
  const int vb0 = lrp * 32 + (((lg >> 1)) ^ vsw) * 8 + (lg & 1) * 4;
  const int vb1 = lrp * 32 + ((2 + (lg >> 1)) ^ vsw) * 8 + (lg & 1) * 4;

  float mrow = -1e30f, lsum = 0.f;
  f32x4 oacc[16] = {};
  int kc = 0, kn2 = 2; // kt%3, (kt+2)%3

  for (int kt = 0; kt < 64; ++kt) {
    const ushort* kl = kb[kc];
    const ushort* vl = vb[kt & 1];

    // S^T = mfma(K, Q): lane holds S[k = n*16+lg*4+r][q = w*16+lr]
    __builtin_amdgcn_s_setprio(1);
    f32x4 s[2] = {};
#pragma unroll
    for (int kk = 0; kk < 8; ++kk) {
#pragma unroll
      for (int n = 0; n < 2; ++n) {
        bf16x8 kv = *(const bf16x8*)&kl[(n * 16 + lr) * 256 + ((kk * 32 + lg * 8) ^ (lr << 4))];
        s[n] = __builtin_amdgcn_mfma_f32_16x16x32_bf16(kv, qf[kk], s[n], 0, 0, 0);
      }
    }
    __builtin_amdgcn_s_setprio(0);

    // issue next tiles: V first, then K (so vmcnt(4) keeps only K(kt+2) in flight)
    if (kt + 1 < 64) stageV(kt + 1, vb[(kt + 1) & 1]);
    if (kt + 2 < 64) stageK(kt + 2, kb[kn2]);

    // online softmax: q-row max = 7 lane-local fmax + 2 shfl
    float tm = fmaxf(fmaxf(fmaxf(s[0][0], s[0][1]), fmaxf(s[0][2], s[0][3])),
                     fmaxf(fmaxf(s[1][0], s[1][1]), fmaxf(s[1][2], s[1][3])));
    tm = fmaxf(tm, __shfl_xor(tm, 16));
    tm = fmaxf(tm, __shfl_xor(tm, 32));

    if (__any(tm > mrow + 11.5f)) { // defer-max: exp2 headroom 2^11.5
      float mn = fmaxf(mrow, tm);
      float alpha = fexp2(mrow - mn);
      mrow = mn;
      lsum *= alpha;
      float ar[4];
#pragma unroll
      for (int r2 = 0; r2 < 4; ++r2) ar[r2] = __shfl(alpha, lg * 4 + r2);
#pragma unroll
      for (int nf = 0; nf < 16; ++nf)
#pragma unroll
        for (int r2 = 0; r2 < 4; ++r2) oacc[nf][r2] *= ar[r2];
    }

    // P = exp2(S - m) packed in-register (lane-local PV A-fragments)
    uint pw[2][2];
#pragma unroll
    for (int n = 0; n < 2; ++n) {
      float p0 = fexp2(s[n][0] - mrow), p1 = fexp2(s[n][1] - mrow);
      float p2 = fexp2(s[n][2] - mrow), p3 = fexp2(s[n][3] - mrow);
      lsum += (p0 + p1) + (p2 + p3);
      asm("v_cvt_pk_bf16_f32 %0, %1, %2" : "=v"(pw[n][0]) : "v"(p0), "v"(p1));
      asm("v_cvt_pk_bf16_f32 %0, %1, %2" : "=v"(pw[n][1]) : "v"(p2), "v"(p3));
    }

    // O += P * V : 2 x 16 mfma_16x16x16, V via swizzled ds_read_b64 (2-way = free)
    __builtin_amdgcn_s_setprio(1);
#pragma unroll
    for (int n = 0; n < 2; ++n) {
      uint2 pk; pk.x = pw[n][0]; pk.y = pw[n][1];
      s16x4 pa = __builtin_bit_cast(s16x4, pk);
      const int vbase = n ? vb1 : vb0;
#pragma unroll
      for (int nf = 0; nf < 16; ++nf) {
        s16x4 vv = *(const s16x4*)&vl[nf * 512 + vbase];
        mfma16(oacc[nf], pa, vv);
      }
    }
    __builtin_amdgcn_s_setprio(0);

    if (kt < 63) {
      if (kt < 62) asm volatile("s_waitcnt vmcnt(4)" ::: "memory");
      else         asm volatile("s_waitcnt vmcnt(0)" ::: "memory");
      __builtin_amdgcn_s_barrier();
    }
    kc = (kc == 2) ? 0 : kc + 1;
    kn2 = (kn2 == 2) ? 0 : kn2 + 1;
  }

  // reduce row-sum across lg groups; write {m, l} and unnormalized partial O
  float ls = lsum;
  ls += __shfl_xor(ls, 16);
  ls += __shfl_xor(ls, 32);

  if (lg == 0) {
    int qp = qt * 64 + w * 16 + lr;
    float2* ml2 = (float2*)ml;
    float2 v; v.x = mrow; v.y = ls;
    ml2[((size_t)(kh * 4 + b)) * 4096 + qp] = v;
  }

  ushort* Ob = (kh ? op1 : op0) + (size_t)b * 4096 * 256;
#pragma unroll
  for (int nf = 0; nf < 16; ++nf) {
#pragma unroll
    for (int r2 = 0; r2 < 4; ++r2) {
      int qp = qt * 64 + w * 16 + lg * 4 + r2;
      Ob[(size_t)qp * 256 + nf * 16 + lr] = f2bf(oacc[nf][r2]);
    }
  }
}

// ---------------- merge the two k-halves: O = (O0*2^(m0-m) + O1*2^(m1-m)) / (l0*2^(m0-m)+l1*2^(m1-m)) ----
__global__ void attn_merge(const ushort* __restrict__ op0, const ushort* __restrict__ op1,
                           const float* __restrict__ ml, ushort* __restrict__ outO) {
  const int g = blockIdx.x * 8 + (threadIdx.x >> 5);
  const int b = g >> 12, p = g & 4095;
  const int d0 = (threadIdx.x & 31) * 8;
  const float2* ml2 = (const float2*)ml;
  float2 a = ml2[(size_t)b * 4096 + p];
  float2 c = ml2[(size_t)(4 + b) * 4096 + p];
  float m = fmaxf(a.x, c.x);
  float e0 = exp2f(a.x - m), e1 = exp2f(c.x - m);
  float inv = 1.f / (a.y * e0 + c.y * e1);
  float w0 = e0 * inv, w1 = e1 * inv;
  const size_t off = ((size_t)b * 4096 + p) * 256 + d0;
  uint4 r0 = *(const uint4*)(op0 + off);
  uint4 r1 = *(const uint4*)(op1 + off);
  uint rr[4] = { r0.x, r0.y, r0.z, r0.w };
  uint ss[4] = { r1.x, r1.y, r1.z, r1.w };
  ushort o[8];
#pragma unroll
  for (int j = 0; j < 4; ++j) {
    o[j * 2]     = f2bf(bflo(rr[j]) * w0 + bflo(ss[j]) * w1);
    o[j * 2 + 1] = f2bf(bfhi(rr[j]) * w0 + bfhi(ss[j]) * w1);
  }
  uint4 wv;
  wv.x = (uint)o[0] | ((uint)o[1] << 16); wv.y = (uint)o[2] | ((uint)o[3] << 16);
  wv.z = (uint)o[4] | ((uint)o[5] << 16); wv.w = (uint)o[6] | ((uint)o[7] << 16);
  *(uint4*)(outO + off) = wv;
}

extern "C" void kernel_launch(void* const* d_in, const int* in_sizes, int n_in,
                              void* d_out, int out_size, void* d_ws, size_t ws_size,
                              hipStream_t stream) {
  const float* x1 = (const float*)d_in[0];
  const float* x2 = (const float*)d_in[1];
  const float* w1 = (const float*)d_in[2];
  const float* b1 = (const float*)d_in[3];
  const float* w2 = (const float*)d_in[4];
  const float* b2 = (const float*)d_in[5];
  const float* gn_w = (const float*)d_in[6];
  const float* gn_b = (const float*)d_in[7];
  const float* wqkv = (const float*)d_in[8];
  const float* wout = (const float*)d_in[9];
  const float* bout = (const float*)d_in[10];
  const float* wsk = (const float*)d_in[11];
  const float* bsk = (const float*)d_in[12];
  float* out = (float*)d_out;

  const size_t NB = (size_t)4 * 4096 * 256;
  ushort* x1t = (ushort*)d_ws;      // later reused as q1t
  ushort* x2t = x1t + NB;           // later reused as k2t
  ushort* y1t = x2t + NB;           // persists (skip input)
  ushort* y2t = y1t + NB;           // GN'd in place -> g2t; later reused as O-partial kh=0
  ushort* g1t = y2t + NB;           // later reused as O-partial kh=1, then merged O
  ushort* v2  = g1t + NB;
  ushort* w1b = v2 + NB;
  ushort* w2b = w1b + 65536;
  ushort* wqb = w2b + 65536;
  ushort* wkvb = wqb + 65536;       // 131072
  ushort* woutb = wkvb + 131072;
  ushort* wskb = woutb + 65536;
  float* mlbuf = (float*)(wskb + 65536); // 2*4*4096 float2 = 512KB

  cast_transpose<<<dim3(128, 8, 8), dim3(32, 8), 0, stream>>>(x1, x2, x1t, x2t);
  cast_weights<<<1792, 256, 0, stream>>>(w1, w2, wqkv, wout, wsk,
                                         w1b, w2b, wqb, wkvb, woutb, wskb);
  conv_pair<<<dim3(2, 32, 8), 256, 0, stream>>>(x1t, x2t, w1b, w2b, b1, b2, y1t, y2t);
  groupnorm<<<dim3(32, 4, 2), 256, 0, stream>>>(y1t, g1t, y2t, gn_w, gn_b);
  gemm_qkv<<<dim3(6, 32, 4), 256, 0, stream>>>(g1t, y2t, wqb, wkvb, x1t, x2t, v2);
  attn<<<512, 256, 0, stream>>>(x1t, x2t, v2, y2t, g1t, mlbuf);
  attn_merge<<<2048, 256, 0, stream>>>(y2t, g1t, mlbuf, g1t);
  gemm_final<<<dim3(2, 32, 4), 256, 0, stream>>>(g1t, y1t, woutb, wskb, bout, bsk, out);
}